// Round 1
// baseline (677.442 us; speedup 1.0000x reference)
//
#include <hip/hip_runtime.h>
#include <hip/hip_bf16.h>

// TreeEncoder: B=64, N=8192, F=64, H=64, L=2. All fp32.
// Per node: h = W_emb@x + b_emb; twice: z_g = Wx[l,g]@h + bW+bU;
// h = sig(z1)*tanh(sig(z0)*tanh(z2)); out = mean_n h.
// Compute-bound on fp32 VALU (no fp32 MFMA): 3.0e10 FLOP -> ~191us floor.

#define NB_ 64
#define NN_ 8192
#define NF_ 64
#define NH_ 64
#define NL_ 2

#if __has_builtin(__builtin_amdgcn_exp2f)
#define EXP2F(x) __builtin_amdgcn_exp2f(x)
#else
#define EXP2F(x) exp2f(x)
#endif
#if __has_builtin(__builtin_amdgcn_rcpf)
#define RCPF(x) __builtin_amdgcn_rcpf(x)
#else
#define RCPF(x) (1.0f / (x))
#endif

__device__ __forceinline__ float fast_sigmoid(float x) {
    // 1/(1+e^-x) = 1/(1+2^(-x*log2e))
    return RCPF(1.0f + EXP2F(-1.4426950408889634f * x));
}
__device__ __forceinline__ float fast_tanh(float x) {
    // tanh(x) = 1 - 2/(e^{2x}+1)
    return 1.0f - 2.0f * RCPF(1.0f + EXP2F(2.8853900817779268f * x));
}

// ws layout (floats):
//   [0, 4096)            emb_t[f][o]   = W_emb[o][f]
//   [4096, 4096+6*4096)  wx_t[l*3+g][i][o] = Wx[l][g][o][i]
//   [28672, 28672+384)   bsum[l*3+g][o] = bW + bU
__global__ void prep_weights(const float* __restrict__ W_emb,
                             const float* __restrict__ Wx,
                             const float* __restrict__ bW,
                             const float* __restrict__ bU,
                             float* __restrict__ ws) {
    int t = blockIdx.x * blockDim.x + threadIdx.x;
    int stride = gridDim.x * blockDim.x;
    for (int idx = t; idx < 64 * 64; idx += stride) {
        int f = idx >> 6, o = idx & 63;
        ws[idx] = W_emb[o * 64 + f];
    }
    for (int idx = t; idx < 6 * 4096; idx += stride) {
        int lg = idx >> 12;
        int r = idx & 4095;
        int i = r >> 6, o = r & 63;
        ws[4096 + lg * 4096 + i * 64 + o] = Wx[lg * 4096 + o * 64 + i];
    }
    for (int idx = t; idx < 6 * 64; idx += stride) {
        ws[28672 + idx] = bW[idx] + bU[idx];
    }
}

__launch_bounds__(256)
__global__ void tree_encoder_kernel(const float* __restrict__ tree,
                                    const float* __restrict__ b_emb,
                                    const float* __restrict__ wt,
                                    float* __restrict__ out) {
    // 68-float row pitch: 16B-aligned rows, lane stride 68 dwords == 4 mod 32
    // -> ds_read_b128 hits the 8-dword/bank floor (conflict-free).
    __shared__ float hbuf[256][68];
    __shared__ float red[4][64];
    const int tid = threadIdx.x;
    const int b = blockIdx.x >> 5;  // 32 blocks per batch

    // ---- stage this block's 256 node rows (coalesced global -> LDS) ----
    const float4* src = (const float4*)(tree + (size_t)blockIdx.x * (256 * 64));
    #pragma unroll
    for (int k = 0; k < 16; ++k) {
        int idx = k * 256 + tid;        // float4 index in [0, 4096)
        float4 v = src[idx];
        int row = idx >> 4;             // 16 float4 per 64-float row
        int c4 = (idx & 15) << 2;
        *(float4*)&hbuf[row][c4] = v;
    }
    __syncthreads();
    // From here on every thread touches ONLY its own LDS row.

    float hn[64];

    // ---- embedding: h[o] = b_emb[o] + sum_f x[f] * emb_t[f][o] ----
    #pragma unroll
    for (int ob = 0; ob < 8; ++ob) {
        float acc[8];
        #pragma unroll
        for (int k = 0; k < 8; ++k) acc[k] = b_emb[ob * 8 + k];  // uniform -> SGPR
        #pragma unroll 1
        for (int i0 = 0; i0 < 64; i0 += 4) {
            float4 xv = *(const float4*)&hbuf[tid][i0];
            const float* wp = wt + i0 * 64 + ob * 8;  // uniform -> s_load
            #pragma unroll
            for (int j = 0; j < 4; ++j) {
                float xj = (j == 0) ? xv.x : (j == 1) ? xv.y : (j == 2) ? xv.z : xv.w;
                #pragma unroll
                for (int k = 0; k < 8; ++k)
                    acc[k] = fmaf(xj, wp[j * 64 + k], acc[k]);
            }
        }
        #pragma unroll
        for (int k = 0; k < 8; ++k) hn[ob * 8 + k] = acc[k];
    }
    // write h back to own row (x is fully consumed)
    #pragma unroll
    for (int o0 = 0; o0 < 64; o0 += 4)
        *(float4*)&hbuf[tid][o0] = make_float4(hn[o0], hn[o0 + 1], hn[o0 + 2], hn[o0 + 3]);

    // ---- 2 TreeLSTM layers (leaf case: forget gate dead, U(h_sum)=bU) ----
    #pragma unroll 1
    for (int l = 0; l < NL_; ++l) {
        const float* wl = wt + 4096 + l * 3 * 4096;   // [g][i][o]
        const float* bl = wt + 28672 + l * 3 * 64;    // [g][o]
        #pragma unroll
        for (int ob = 0; ob < 8; ++ob) {
            float z0[8], z1[8], z2[8];
            #pragma unroll
            for (int k = 0; k < 8; ++k) {
                z0[k] = bl[0 * 64 + ob * 8 + k];
                z1[k] = bl[1 * 64 + ob * 8 + k];
                z2[k] = bl[2 * 64 + ob * 8 + k];
            }
            #pragma unroll 1
            for (int i0 = 0; i0 < 64; i0 += 4) {
                float4 hv = *(const float4*)&hbuf[tid][i0];
                const float* wp = wl + i0 * 64 + ob * 8;
                #pragma unroll
                for (int j = 0; j < 4; ++j) {
                    float hj = (j == 0) ? hv.x : (j == 1) ? hv.y : (j == 2) ? hv.z : hv.w;
                    #pragma unroll
                    for (int k = 0; k < 8; ++k) {
                        z0[k] = fmaf(hj, wp[0 * 4096 + j * 64 + k], z0[k]);
                        z1[k] = fmaf(hj, wp[1 * 4096 + j * 64 + k], z1[k]);
                        z2[k] = fmaf(hj, wp[2 * 4096 + j * 64 + k], z2[k]);
                    }
                }
            }
            #pragma unroll
            for (int k = 0; k < 8; ++k) {
                float ig = fast_sigmoid(z0[k]);
                float og = fast_sigmoid(z1[k]);
                float ct = fast_tanh(z2[k]);
                float c = ig * ct;
                hn[ob * 8 + k] = og * fast_tanh(c);
            }
        }
        #pragma unroll
        for (int o0 = 0; o0 < 64; o0 += 4)
            *(float4*)&hbuf[tid][o0] = make_float4(hn[o0], hn[o0 + 1], hn[o0 + 2], hn[o0 + 3]);
    }

    // ---- block reduction: mean over nodes ----
    __syncthreads();
    {
        const int c = tid & 63;
        const int q = tid >> 6;
        float s = 0.0f;
        #pragma unroll 1
        for (int t = 0; t < 64; ++t) s += hbuf[q * 64 + t][c];
        red[q][c] = s;
    }
    __syncthreads();
    if (tid < 64) {
        float v = (red[0][tid] + red[1][tid] + red[2][tid] + red[3][tid]) * (1.0f / 8192.0f);
        atomicAdd(&out[b * 64 + tid], v);
    }
}

extern "C" void kernel_launch(void* const* d_in, const int* in_sizes, int n_in,
                              void* d_out, int out_size, void* d_ws, size_t ws_size,
                              hipStream_t stream) {
    const float* tree  = (const float*)d_in[0];
    const float* W_emb = (const float*)d_in[1];
    const float* b_emb = (const float*)d_in[2];
    const float* Wx    = (const float*)d_in[3];
    const float* bW    = (const float*)d_in[4];
    const float* bU    = (const float*)d_in[5];
    float* outp = (float*)d_out;
    float* ws   = (float*)d_ws;

    // harness poisons d_out before timing; we zero it every launch
    hipMemsetAsync(d_out, 0, (size_t)out_size * sizeof(float), stream);
    prep_weights<<<32, 256, 0, stream>>>(W_emb, Wx, bW, bU, ws);
    tree_encoder_kernel<<<2048, 256, 0, stream>>>(tree, b_emb, ws, outp);
}

// Round 2
// 162.813 us; speedup vs baseline: 4.1608x; 4.1608x over previous
//
#include <hip/hip_runtime.h>
#include <hip/hip_bf16.h>

// TreeEncoder B=64,N=8192,F=H=64,L=2 — split-bf16 MFMA formulation.
// Per layer: Z[node,192] = h[node,64] @ Wt[64,192] + bias; gates elementwise.
// fp32 = hi(bf16) + lo(bf16); keep hi*hi + hi*lo + lo*hi (3 MFMAs per product).
// MFMA floor ~43us, trans ~27us, VALU ~21us, HBM ~21us (overlapping pipes).

typedef __attribute__((ext_vector_type(4))) float f32x4;
typedef __attribute__((ext_vector_type(8))) short s16x8;

#if __has_builtin(__builtin_amdgcn_exp2f)
#define EXP2F(x) __builtin_amdgcn_exp2f(x)
#else
#define EXP2F(x) exp2f(x)
#endif
#if __has_builtin(__builtin_amdgcn_rcpf)
#define RCPF(x) __builtin_amdgcn_rcpf(x)
#else
#define RCPF(x) (1.0f / (x))
#endif

__device__ __forceinline__ float fast_sigmoid(float x) {
    return RCPF(1.0f + EXP2F(-1.4426950408889634f * x));
}
__device__ __forceinline__ float fast_tanh(float x) {
    return 1.0f - 2.0f * RCPF(1.0f + EXP2F(2.8853900817779268f * x));
}

__device__ __forceinline__ unsigned short rne_bf16(float f) {
    unsigned u = __builtin_bit_cast(unsigned, f);
    return (unsigned short)((u + 0x7fffu + ((u >> 16) & 1u)) >> 16);
}
__device__ __forceinline__ float bf16_f(unsigned short h) {
    unsigned u = ((unsigned)h) << 16;
    return __builtin_bit_cast(float, u);
}

// ---------------------------------------------------------------------------
// ws layout:
//   u16 wfrag[112 * 512]          (7 mats x 2 splits x 2 kk x 4 nt) x 64 lanes x 8
//     frag element j of lane l = split_s( M[n][k] ),
//     n = nt*16 + (l&15), k = (l>>4)*8 + kk*32 + j     (B[k][n] = M[n][k])
//   f32 wbias[7*64] at byte offset 114688   (mat0: b_emb; mat 1+l*3+g: bW+bU)
// ---------------------------------------------------------------------------
__global__ void prep_weights(const float* __restrict__ W_emb,
                             const float* __restrict__ b_emb,
                             const float* __restrict__ Wx,
                             const float* __restrict__ bW,
                             const float* __restrict__ bU,
                             unsigned short* __restrict__ wfrag,
                             float* __restrict__ wbias) {
    int t = blockIdx.x * 256 + threadIdx.x;
    if (t < 448) {
        int mat = t >> 6, o = t & 63;
        wbias[t] = (mat == 0) ? b_emb[o] : (bW[(mat - 1) * 64 + o] + bU[(mat - 1) * 64 + o]);
    }
    if (t < 28672) {  // (mat,kk,nt,lane,j)
        int j = t & 7, lane = (t >> 3) & 63, nt = (t >> 9) & 3, kk = (t >> 11) & 1, mat = t >> 12;
        int n = nt * 16 + (lane & 15);
        int k = (lane >> 4) * 8 + kk * 32 + j;
        float wv = (mat == 0) ? W_emb[n * 64 + k] : Wx[(mat - 1) * 4096 + n * 64 + k];
        unsigned short hi = rne_bf16(wv);
        unsigned short lo = rne_bf16(wv - bf16_f(hi));
        wfrag[(((mat * 2 + 0) * 2 + kk) * 4 + nt) * 512 + lane * 8 + j] = hi;
        wfrag[(((mat * 2 + 1) * 2 + kk) * 4 + nt) * 512 + lane * 8 + j] = lo;
    }
}

// ---------------------------------------------------------------------------
// Main kernel: 64 nodes/block, 4 waves, wave w owns nodes [blk*64+w*16, +16).
// A-frag (16x32 bf16): lane holds row m=l&15, k = 8*(l>>4)+32*kk+j (contiguous).
// C/D: lane l reg r -> C[m=(l>>4)*4+r][n = nt*16 + (l&15)]  (m89-verified).
// h tile lives in per-wave LDS region, XOR-swizzled: u16 idx = m*64 + (n ^ ((m&7)<<3))
// -> the 64-lane ds_read_b128 hits the 8-slot/128B floor (conflict-free).
// ---------------------------------------------------------------------------
__global__ __launch_bounds__(256, 2) void tree_encoder_mfma(
        const float* __restrict__ tree,
        const unsigned short* __restrict__ wfrag,
        const float* __restrict__ wbias,
        float* __restrict__ out) {
    __shared__ unsigned short lds_h[4][2][1024];  // [wave][split][16 rows x 64]
    __shared__ float red[4][64];
    const int tid = threadIdx.x;
    const int w = tid >> 6, lane = tid & 63;
    const int lg = lane >> 4, lr = lane & 15;
    const s16x8* wf = (const s16x8*)wfrag;

    float hcur[16];  // [nt*4 + r]

    // ---------------- embedding: A from global, split in-register ----------
    {
        s16x8 ahi[2], alo[2];
        const float* src = tree + ((size_t)blockIdx.x * 64 + w * 16 + lr) * 64 + lg * 8;
#pragma unroll
        for (int kk = 0; kk < 2; ++kk) {
            float v[8];
            *(float4*)&v[0] = *(const float4*)(src + kk * 32);
            *(float4*)&v[4] = *(const float4*)(src + kk * 32 + 4);
#pragma unroll
            for (int j = 0; j < 8; ++j) {
                unsigned short h = rne_bf16(v[j]);
                ahi[kk][j] = (short)h;
                alo[kk][j] = (short)rne_bf16(v[j] - bf16_f(h));
            }
        }
        f32x4 acc[4];
#pragma unroll
        for (int nt = 0; nt < 4; ++nt) {
            float bv = wbias[nt * 16 + lr];
            acc[nt] = f32x4{bv, bv, bv, bv};
        }
#pragma unroll
        for (int nt = 0; nt < 4; ++nt) {
#pragma unroll
            for (int kk = 0; kk < 2; ++kk) {
                s16x8 bhi = wf[(((0 * 2 + 0) * 2 + kk) * 4 + nt) * 64 + lane];
                s16x8 blo = wf[(((0 * 2 + 1) * 2 + kk) * 4 + nt) * 64 + lane];
                acc[nt] = __builtin_amdgcn_mfma_f32_16x16x32_bf16(ahi[kk], bhi, acc[nt], 0, 0, 0);
                acc[nt] = __builtin_amdgcn_mfma_f32_16x16x32_bf16(ahi[kk], blo, acc[nt], 0, 0, 0);
                acc[nt] = __builtin_amdgcn_mfma_f32_16x16x32_bf16(alo[kk], bhi, acc[nt], 0, 0, 0);
            }
        }
#pragma unroll
        for (int nt = 0; nt < 4; ++nt)
#pragma unroll
            for (int r = 0; r < 4; ++r) hcur[nt * 4 + r] = acc[nt][r];
    }

    // write h (split) to own LDS region
#pragma unroll
    for (int nt = 0; nt < 4; ++nt)
#pragma unroll
        for (int r = 0; r < 4; ++r) {
            int m = lg * 4 + r;
            int idx = m * 64 + ((nt * 16 + lr) ^ ((m & 7) << 3));
            float hv = hcur[nt * 4 + r];
            unsigned short hb = rne_bf16(hv);
            lds_h[w][0][idx] = hb;
            lds_h[w][1][idx] = rne_bf16(hv - bf16_f(hb));
        }
    __syncthreads();

    // ---------------- 2 TreeLSTM layers ----------------
#pragma unroll
    for (int l = 0; l < 2; ++l) {
        s16x8 Ahi[2], Alo[2];
#pragma unroll
        for (int kk = 0; kk < 2; ++kk) {
            int ridx = lr * 64 + ((lg * 8 + kk * 32) ^ ((lr & 7) << 3));
            Ahi[kk] = *(const s16x8*)&lds_h[w][0][ridx];
            Alo[kk] = *(const s16x8*)&lds_h[w][1][ridx];
        }
        f32x4 acc[12];  // t = g*4 + nt
#pragma unroll
        for (int g = 0; g < 3; ++g)
#pragma unroll
            for (int nt = 0; nt < 4; ++nt) {
                float bv = wbias[(1 + l * 3 + g) * 64 + nt * 16 + lr];
                acc[g * 4 + nt] = f32x4{bv, bv, bv, bv};
            }
#pragma unroll
        for (int g = 0; g < 3; ++g)
#pragma unroll
            for (int nt = 0; nt < 4; ++nt) {
                const int mat = 1 + l * 3 + g;
#pragma unroll
                for (int kk = 0; kk < 2; ++kk) {
                    s16x8 bhi = wf[(((mat * 2 + 0) * 2 + kk) * 4 + nt) * 64 + lane];
                    s16x8 blo = wf[(((mat * 2 + 1) * 2 + kk) * 4 + nt) * 64 + lane];
                    f32x4 a = acc[g * 4 + nt];
                    a = __builtin_amdgcn_mfma_f32_16x16x32_bf16(Ahi[kk], bhi, a, 0, 0, 0);
                    a = __builtin_amdgcn_mfma_f32_16x16x32_bf16(Ahi[kk], blo, a, 0, 0, 0);
                    a = __builtin_amdgcn_mfma_f32_16x16x32_bf16(Alo[kk], bhi, a, 0, 0, 0);
                    acc[g * 4 + nt] = a;
                }
            }
        // gates (pure per-lane: i,o,c~ share the same (m,n) position)
#pragma unroll
        for (int nt = 0; nt < 4; ++nt)
#pragma unroll
            for (int r = 0; r < 4; ++r) {
                float ig = fast_sigmoid(acc[nt][r]);
                float og = fast_sigmoid(acc[4 + nt][r]);
                float ct = fast_tanh(acc[8 + nt][r]);
                hcur[nt * 4 + r] = og * fast_tanh(ig * ct);
            }
        if (l == 0) {
            __syncthreads();  // reads above must complete before overwrite
#pragma unroll
            for (int nt = 0; nt < 4; ++nt)
#pragma unroll
                for (int r = 0; r < 4; ++r) {
                    int m = lg * 4 + r;
                    int idx = m * 64 + ((nt * 16 + lr) ^ ((m & 7) << 3));
                    float hv = hcur[nt * 4 + r];
                    unsigned short hb = rne_bf16(hv);
                    lds_h[w][0][idx] = hb;
                    lds_h[w][1][idx] = rne_bf16(hv - bf16_f(hb));
                }
            __syncthreads();
        }
    }

    // ---------------- mean over nodes ----------------
#pragma unroll
    for (int nt = 0; nt < 4; ++nt) {
        float s = hcur[nt * 4] + hcur[nt * 4 + 1] + hcur[nt * 4 + 2] + hcur[nt * 4 + 3];
        s += __shfl_xor(s, 16);
        s += __shfl_xor(s, 32);
        if (lg == 0) red[w][nt * 16 + lr] = s;
    }
    __syncthreads();
    if (tid < 64) {
        float v = (red[0][tid] + red[1][tid] + red[2][tid] + red[3][tid]) * (1.0f / 8192.0f);
        atomicAdd(&out[(blockIdx.x >> 7) * 64 + tid], v);
    }
}

extern "C" void kernel_launch(void* const* d_in, const int* in_sizes, int n_in,
                              void* d_out, int out_size, void* d_ws, size_t ws_size,
                              hipStream_t stream) {
    const float* tree  = (const float*)d_in[0];
    const float* W_emb = (const float*)d_in[1];
    const float* b_emb = (const float*)d_in[2];
    const float* Wx    = (const float*)d_in[3];
    const float* bW    = (const float*)d_in[4];
    const float* bU    = (const float*)d_in[5];
    float* outp = (float*)d_out;
    unsigned short* wfrag = (unsigned short*)d_ws;
    float* wbias = (float*)((char*)d_ws + 112 * 512 * sizeof(unsigned short));

    hipMemsetAsync(d_out, 0, (size_t)out_size * sizeof(float), stream);
    prep_weights<<<112, 256, 0, stream>>>(W_emb, b_emb, Wx, bW, bU, wfrag, wbias);
    tree_encoder_mfma<<<8192, 256, 0, stream>>>(tree, wfrag, wbias, outp);
}

// Round 3
// 138.652 us; speedup vs baseline: 4.8859x; 1.1743x over previous
//
#include <hip/hip_runtime.h>
#include <hip/hip_bf16.h>

// TreeEncoder B=64,N=8192,F=H=64,L=2 — transposed persistent-weight MFMA.
// Z^T[192, nodes] = W[192,64] @ h^T[64, nodes]; weights (split hi/lo bf16)
// live in 112 VGPRs per wave, loaded once per block. x streams HBM->LDS via
// global_load_lds; h exchanged via XOR-swizzled LDS planes.
// Floors: matrix pipe 43.5us, VALU+trans ~50us, HBM 21us.

typedef __attribute__((ext_vector_type(4))) float f32x4;
typedef __attribute__((ext_vector_type(8))) short s16x8;
typedef __attribute__((ext_vector_type(4))) short s16x4;

#if __has_builtin(__builtin_amdgcn_exp2f)
#define EXP2F(x) __builtin_amdgcn_exp2f(x)
#else
#define EXP2F(x) exp2f(x)
#endif
#if __has_builtin(__builtin_amdgcn_rcpf)
#define RCPF(x) __builtin_amdgcn_rcpf(x)
#else
#define RCPF(x) (1.0f / (x))
#endif

__device__ __forceinline__ float fast_sigmoid(float x) {
    return RCPF(1.0f + EXP2F(-1.4426950408889634f * x));
}
__device__ __forceinline__ float fast_tanh(float x) {
    return 1.0f - 2.0f * RCPF(1.0f + EXP2F(2.8853900817779268f * x));
}

__device__ __forceinline__ unsigned short bfhi(float f) {  // RNE to bf16
    unsigned u = __builtin_bit_cast(unsigned, f);
    return (unsigned short)((u + 0x7fffu + ((u >> 16) & 1u)) >> 16);
}
__device__ __forceinline__ float bff(unsigned short h) {
    unsigned u = ((unsigned)h) << 16;
    return __builtin_bit_cast(float, u);
}

// ---------------------------------------------------------------------------
// ws layout:
//   u16 wfrag[112*512]: A-frag fid = ((mat*4 + w)*2 + kk)*2 + sp
//     lane l elem j = split_sp( M[o][k] ), o = w*16+(l&15), k = 8*(l>>4)+kk*32+j
//     mat0 = W_emb, mat 1+l*3+g = Wx[l][g]
//   f32 wbias[7*64] @ byte 114688: mat0 = b_emb, else bW+bU
// ---------------------------------------------------------------------------
__global__ void prep_weights(const float* __restrict__ W_emb,
                             const float* __restrict__ b_emb,
                             const float* __restrict__ Wx,
                             const float* __restrict__ bW,
                             const float* __restrict__ bU,
                             unsigned short* __restrict__ wfrag,
                             float* __restrict__ wbias) {
    int t = blockIdx.x * 256 + threadIdx.x;
    if (t < 448) {
        int mat = t >> 6, o = t & 63;
        wbias[t] = (mat == 0) ? b_emb[o] : (bW[(mat - 1) * 64 + o] + bU[(mat - 1) * 64 + o]);
    }
    if (t < 57344) {
        int j = t & 7, lane = (t >> 3) & 63;
        int fid = t >> 9;
        int sp = fid & 1, kk = (fid >> 1) & 1, wv = (fid >> 2) & 3, mat = fid >> 4;
        int o = wv * 16 + (lane & 15);
        int k = ((lane >> 4) << 3) + kk * 32 + j;
        float v = (mat == 0) ? W_emb[o * 64 + k] : Wx[(mat - 1) * 4096 + o * 64 + k];
        unsigned short hi = bfhi(v);
        wfrag[t] = sp ? bfhi(v - bff(hi)) : hi;
    }
}

// ---------------------------------------------------------------------------
// Main: 512 blocks x 256 thr; block handles 16 tiles of 64 nodes (1024 nodes,
// all in batch blockIdx.x>>3). Wave w owns Z-rows {g*64 + w*16 .. +16}.
// A row = lane&15, k = 8*(lane>>4)+kk*32+j; B col(node) = lane&15, same k;
// C row(dim) = 4*(lane>>4)+r, col(node) = lane&15.   (round-2-validated)
// x LDS: float[node][col4 ^ ((node&7)<<1)] (src pre-swizzled for gl_lds).
// h LDS: u16[node][dim ^ ((node&7)<<3)], hi/lo planes.
// ---------------------------------------------------------------------------
__global__ __launch_bounds__(256, 2) void tree_encoder_mfma(
        const float* __restrict__ tree,
        const unsigned short* __restrict__ wfrag,
        const float* __restrict__ wbias,
        float* __restrict__ out) {
    __shared__ float xbuf[2][4096];          // 2 x 16 KB, swizzled
    __shared__ unsigned short hh[2][4096];   // plane 0: emb out, plane 1: layer0 out
    __shared__ unsigned short hl[2][4096];
    const int tid = threadIdx.x;
    const int w = tid >> 6, lane = tid & 63;
    const int lg = lane >> 4, lr = lane & 15;

    // ---- persistent weight A-frags: 28 x s16x8 = 112 VGPR ----
    s16x8 wA[28];
#pragma unroll
    for (int m = 0; m < 7; ++m)
#pragma unroll
        for (int kk = 0; kk < 2; ++kk)
#pragma unroll
            for (int sp = 0; sp < 2; ++sp)
                wA[(m * 2 + kk) * 2 + sp] = *(const s16x8*)(
                    wfrag + (((((m * 4 + w) * 2 + kk) * 2 + sp) << 9) + lane * 8));

    float nsum[4] = {0.f, 0.f, 0.f, 0.f};
    const int t0 = blockIdx.x * 16;

    auto stage = [&](int pp, int t) {
#pragma unroll
        for (int v = 0; v < 4; ++v) {
            int vv = (w << 2) + v;          // 1KB chunk id
            int node = (vv << 2) + lg;
            int tc4 = lr ^ ((node & 7) << 1);
            const float* src = tree + (size_t)((t << 6) + node) * 64 + (tc4 << 2);
            __builtin_amdgcn_global_load_lds(
                (const __attribute__((address_space(1))) unsigned int*)src,
                (__attribute__((address_space(3))) unsigned int*)&xbuf[pp][vv << 8], 16, 0, 0);
        }
    };

    stage(0, t0);  // prologue prefetch
    int p = 0;

#pragma unroll 1
    for (int ti = 0; ti < 16; ++ti) {
        const int t = t0 + ti;
        __syncthreads();                    // x[p] staged; h planes free
        if (ti < 15) stage(p ^ 1, t + 1);   // overlap with emb phase

        // ---------- embedding: h0 = W_emb @ x + b ----------
        {
            const f32x4 be = *(const f32x4*)(wbias + w * 16 + 4 * lg);
#pragma unroll
            for (int nt = 0; nt < 4; ++nt) {
                const int n = nt * 16 + lr;
                const int sw2 = (n & 7) << 1;
                f32x4 acc = be;
#pragma unroll
                for (int kk = 0; kk < 2; ++kk) {
                    const int c4 = 2 * lg + 8 * kk;
                    f32x4 xa = *(const f32x4*)&xbuf[p][(n << 6) + (((c4) ^ sw2) << 2)];
                    f32x4 xb = *(const f32x4*)&xbuf[p][(n << 6) + (((c4 + 1) ^ sw2) << 2)];
                    s16x8 bh, bl;
#pragma unroll
                    for (int j = 0; j < 4; ++j) {
                        unsigned short h0 = bfhi(xa[j]);
                        bh[j] = (short)h0; bl[j] = (short)bfhi(xa[j] - bff(h0));
                        unsigned short h1 = bfhi(xb[j]);
                        bh[4 + j] = (short)h1; bl[4 + j] = (short)bfhi(xb[j] - bff(h1));
                    }
                    acc = __builtin_amdgcn_mfma_f32_16x16x32_bf16(wA[kk * 2], bh, acc, 0, 0, 0);
                    acc = __builtin_amdgcn_mfma_f32_16x16x32_bf16(wA[kk * 2], bl, acc, 0, 0, 0);
                    acc = __builtin_amdgcn_mfma_f32_16x16x32_bf16(wA[kk * 2 + 1], bh, acc, 0, 0, 0);
                }
                const int dsw = (n & 7) << 3;
                const int db = (w * 16 + 4 * lg) ^ dsw;
                s16x4 ph, plo;
#pragma unroll
                for (int r = 0; r < 4; ++r) {
                    unsigned short hi = bfhi(acc[r]);
                    ph[r] = (short)hi;
                    plo[r] = (short)bfhi(acc[r] - bff(hi));
                }
                *(s16x4*)&hh[0][(n << 6) + db] = ph;
                *(s16x4*)&hl[0][(n << 6) + db] = plo;
            }
        }
        __syncthreads();  // h0 ready

        // ---------- layers ----------
        auto layer = [&](const int l, const int pl, const bool last) {
            f32x4 acc[3][4];
#pragma unroll
            for (int g = 0; g < 3; ++g) {
                const f32x4 bg = *(const f32x4*)(wbias + (1 + l * 3 + g) * 64 + w * 16 + 4 * lg);
#pragma unroll
                for (int nt = 0; nt < 4; ++nt) acc[g][nt] = bg;
            }
#pragma unroll
            for (int nt = 0; nt < 4; ++nt) {
                const int n = nt * 16 + lr;
                const int dsw = (n & 7) << 3;
#pragma unroll
                for (int kk = 0; kk < 2; ++kk) {
                    const int d0 = (8 * lg + 32 * kk) ^ dsw;
                    s16x8 bh = *(const s16x8*)&hh[pl][(n << 6) + d0];
                    s16x8 bl = *(const s16x8*)&hl[pl][(n << 6) + d0];
#pragma unroll
                    for (int g = 0; g < 3; ++g) {
                        const int wb = ((1 + l * 3 + g) * 2 + kk) * 2;
                        f32x4 a = acc[g][nt];
                        a = __builtin_amdgcn_mfma_f32_16x16x32_bf16(wA[wb], bh, a, 0, 0, 0);
                        a = __builtin_amdgcn_mfma_f32_16x16x32_bf16(wA[wb], bl, a, 0, 0, 0);
                        a = __builtin_amdgcn_mfma_f32_16x16x32_bf16(wA[wb + 1], bh, a, 0, 0, 0);
                        acc[g][nt] = a;
                    }
                }
                // gates for this nt (i=g0, o=g1, c~=g2)
                if (last) {
#pragma unroll
                    for (int r = 0; r < 4; ++r) {
                        float ig = fast_sigmoid(acc[0][nt][r]);
                        float og = fast_sigmoid(acc[1][nt][r]);
                        float ct = fast_tanh(acc[2][nt][r]);
                        nsum[r] += og * fast_tanh(ig * ct);
                    }
                } else {
                    const int db = (w * 16 + 4 * lg) ^ dsw;
                    s16x4 ph, plo;
#pragma unroll
                    for (int r = 0; r < 4; ++r) {
                        float ig = fast_sigmoid(acc[0][nt][r]);
                        float og = fast_sigmoid(acc[1][nt][r]);
                        float ct = fast_tanh(acc[2][nt][r]);
                        float hv = og * fast_tanh(ig * ct);
                        unsigned short hi = bfhi(hv);
                        ph[r] = (short)hi;
                        plo[r] = (short)bfhi(hv - bff(hi));
                    }
                    *(s16x4*)&hh[1][(n << 6) + db] = ph;
                    *(s16x4*)&hl[1][(n << 6) + db] = plo;
                }
            }
        };

        layer(0, 0, false);
        __syncthreads();  // h1 ready
        layer(1, 1, true);

        p ^= 1;
    }

    // ---- reduce over lr group (16 node-columns) and emit ----
#pragma unroll
    for (int r = 0; r < 4; ++r) {
        float s = nsum[r];
        s += __shfl_xor(s, 1);
        s += __shfl_xor(s, 2);
        s += __shfl_xor(s, 4);
        s += __shfl_xor(s, 8);
        if (lr == 0)
            atomicAdd(&out[(blockIdx.x >> 3) * 64 + w * 16 + 4 * lg + r], s * (1.0f / 8192.0f));
    }
}

extern "C" void kernel_launch(void* const* d_in, const int* in_sizes, int n_in,
                              void* d_out, int out_size, void* d_ws, size_t ws_size,
                              hipStream_t stream) {
    const float* tree  = (const float*)d_in[0];
    const float* W_emb = (const float*)d_in[1];
    const float* b_emb = (const float*)d_in[2];
    const float* Wx    = (const float*)d_in[3];
    const float* bW    = (const float*)d_in[4];
    const float* bU    = (const float*)d_in[5];
    float* outp = (float*)d_out;
    unsigned short* wfrag = (unsigned short*)d_ws;
    float* wbias = (float*)((char*)d_ws + 112 * 512 * sizeof(unsigned short));

    hipMemsetAsync(d_out, 0, (size_t)out_size * sizeof(float), stream);
    prep_weights<<<224, 256, 0, stream>>>(W_emb, b_emb, Wx, bW, bU, wfrag, wbias);
    tree_encoder_mfma<<<512, 256, 0, stream>>>(tree, wfrag, wbias, outp);
}